// Round 8
// baseline (219.333 us; speedup 1.0000x reference)
//
#include <hip/hip_runtime.h>
#include <hip/hip_bf16.h>
#include <cstdint>
#include <cmath>

#define T_TOK 8192
#define HD 1024
#define ID 512
#define NE 8
#define BM 128
#define BK 64
#define MAXMT (T_TOK / BM)   // 64

#define GU_BN 64
#define GU_SPACE (MAXMT * (ID / GU_BN))   // 512; active ~64-72/expert
#define GU_BPE 64
#define GU_GRID (NE * GU_BPE)             // 512 -> 2 blocks/CU
#define DN_BN 128
#define DN_SPACE (MAXMT * (HD / DN_BN))   // 512; active ~64-72/expert
#define DN_BPE 64
#define DN_GRID (NE * DN_BPE)             // 512 -> 2 blocks/CU

#define CAST_BLOCKS ((NE * ID * HD / 4) / 256)   // 4096
#define RESC_MAX 2048
#define GAP_THR 0.06f

typedef __attribute__((ext_vector_type(8))) short short8;
typedef __attribute__((ext_vector_type(4))) float f32x4;

__device__ __forceinline__ unsigned short f2bf(float f) {
  union { float f; unsigned int u; } v; v.f = f;
  unsigned int u = v.u;
  u += 0x7fffu + ((u >> 16) & 1u);   // RNE
  return (unsigned short)(u >> 16);
}

#if __has_builtin(__builtin_amdgcn_global_load_lds)
#define HAVE_GLDS 1
#endif

// Global->LDS 16B/lane. LDS dest = wave-uniform base + lane*16.
__device__ __forceinline__ void stage16(const ushort* __restrict__ g,
                                        ushort* lds_wave_base, int lane) {
#ifdef HAVE_GLDS
  __builtin_amdgcn_global_load_lds((const __attribute__((address_space(1))) void*)g,
                                   (__attribute__((address_space(3))) void*)lds_wave_base,
                                   16, 0, 0);
#else
  *(uint4*)(lds_wave_base + (size_t)lane * 8) = *(const uint4*)g;
#endif
}

// BK=64: one glds instr stages 8 rows x 128B. Lane l -> row rl=l>>3, dest slot c=l&7.
// Slot c holds global colgroup c ^ (rl&7) (XOR swizzle; verified 0 bank conflicts).
__device__ __forceinline__ void stageChunk(const ushort* __restrict__ rowbase, size_t ld,
                                           int k0, ushort* ldsChunk, int lane) {
  int rl = lane >> 3;
  int gc = (lane & 7) ^ (rl & 7);
  stage16(rowbase + (size_t)rl * ld + k0 + gc * 8, ldsChunk, lane);
}

// Read 8-elem bf16 frag at (row r, global colgroup g), undoing swizzle.
__device__ __forceinline__ short8 fragRd(const ushort* buf, int r, int g) {
  int slot = g ^ (r & 7);
  return *(const short8*)&buf[r * BK + slot * 8];
}

__device__ __forceinline__ short8 cvt8(float4 a, float4 b) {
  short8 r;
  r[0] = (short)f2bf(a.x); r[1] = (short)f2bf(a.y);
  r[2] = (short)f2bf(a.z); r[3] = (short)f2bf(a.w);
  r[4] = (short)f2bf(b.x); r[5] = (short)f2bf(b.y);
  r[6] = (short)f2bf(b.z); r[7] = (short)f2bf(b.w);
  return r;
}

// ---------------- logits via bf16 MFMA + fused argmax/gap-rescue ----------------
// Block = 16 tokens; 4 waves split K (256 each); LDS reduce; threads 0-15 argmax.
__global__ __launch_bounds__(256) void k_logits_sel(const float* __restrict__ x,
                                                    const float* __restrict__ gw,
                                                    int* __restrict__ sel,
                                                    int* __restrict__ rlist,
                                                    int* __restrict__ rcnt) {
  __shared__ float red[4][16][16];
  int tid = threadIdx.x, wv = tid >> 6, lane = tid & 63;
  int tb = blockIdx.x * 16;
  int quad = lane >> 4, colv = lane & 15;
  bool bvalid = colv < 8;

  const float* xrow = x + (size_t)(tb + colv) * HD + wv * 256 + quad * 8;
  const float* gwrow = gw + (size_t)(colv & 7) * HD + wv * 256 + quad * 8;

  f32x4 acc = {};
  short8 bz = {};
#pragma unroll
  for (int ks = 0; ks < 8; ks++) {
    float4 a0 = *(const float4*)(xrow + ks * 32);
    float4 a1 = *(const float4*)(xrow + ks * 32 + 4);
    short8 af = cvt8(a0, a1);
    short8 bf8 = bz;
    if (bvalid) {
      float4 b0 = *(const float4*)(gwrow + ks * 32);
      float4 b1 = *(const float4*)(gwrow + ks * 32 + 4);
      bf8 = cvt8(b0, b1);
    }
    acc = __builtin_amdgcn_mfma_f32_16x16x32_bf16(af, bf8, acc, 0, 0, 0);
  }
#pragma unroll
  for (int r = 0; r < 4; r++) red[wv][quad * 4 + r][colv] = acc[r];
  __syncthreads();
  int rr = tid >> 4, cc = tid & 15;
  float s = red[0][rr][cc] + red[1][rr][cc] + red[2][rr][cc] + red[3][rr][cc];
  __syncthreads();
  red[0][rr][cc] = s;
  __syncthreads();
  if (tid < 16) {
    float best = -1e30f, sec = -1e30f; int bi = 0;
#pragma unroll
    for (int e = 0; e < NE; e++) {
      float v = red[0][tid][e];
      if (v > best) { sec = best; best = v; bi = e; }
      else if (v > sec) sec = v;
    }
    sel[tb + tid] = bi;
    if (best - sec < GAP_THR) {
      int ix = atomicAdd(rcnt, 1);
      if (ix < RESC_MAX) rlist[ix] = tb + tid;
    }
  }
}

// ---------------- rescue: exact fp64 argmax for narrow-gap tokens ----------------
__global__ __launch_bounds__(256) void k_rescue(const float* __restrict__ x,
                                                const float* __restrict__ gw,
                                                const int* __restrict__ rlist,
                                                const int* __restrict__ rcnt,
                                                int* __restrict__ sel) {
  int wi = blockIdx.x * 4 + (threadIdx.x >> 6);
  int n = *rcnt; if (n > RESC_MAX) n = RESC_MAX;
  if (wi >= n) return;
  int lane = threadIdx.x & 63;
  int t = rlist[wi];
  const float4* xr = (const float4*)(x + (size_t)t * HD);
  double acc[NE];
#pragma unroll
  for (int e = 0; e < NE; e++) acc[e] = 0.0;
#pragma unroll
  for (int j = 0; j < 4; j++) {
    float4 xv = xr[lane + 64 * j];
#pragma unroll
    for (int e = 0; e < NE; e++) {
      float4 wv4 = ((const float4*)(gw + e * HD))[lane + 64 * j];
      acc[e] += (double)xv.x * wv4.x + (double)xv.y * wv4.y +
                (double)xv.z * wv4.z + (double)xv.w * wv4.w;
    }
  }
#pragma unroll
  for (int e = 0; e < NE; e++)
    for (int off = 32; off >= 1; off >>= 1)
      acc[e] += __shfl_xor(acc[e], off);
  if (lane == 0) {
    double best = acc[0]; int bi = 0;
#pragma unroll
    for (int e = 1; e < NE; e++) if (acc[e] > best) { best = acc[e]; bi = e; }
    sel[t] = bi;
  }
}

// ---------------- single-block count + scan + permutation (no atomics) ----------
__global__ __launch_bounds__(1024) void k_scan(const int* __restrict__ sel,
                                               int* __restrict__ cnt,
                                               int* __restrict__ perm) {
  __shared__ int wbase[NE][16];
  __shared__ int off[NE];
  int tid = threadIdx.x;
  int wv = tid >> 6, lane = tid & 63;

  int4 s0 = ((const int4*)sel)[tid * 2];
  int4 s1 = ((const int4*)sel)[tid * 2 + 1];
  int sl[8] = {s0.x, s0.y, s0.z, s0.w, s1.x, s1.y, s1.z, s1.w};

  int c[NE];
#pragma unroll
  for (int e = 0; e < NE; e++) c[e] = 0;
#pragma unroll
  for (int i = 0; i < 8; i++)
#pragma unroll
    for (int e = 0; e < NE; e++) c[e] += (sl[i] == e) ? 1 : 0;

  int pre[NE];
#pragma unroll
  for (int e = 0; e < NE; e++) {
    int v = c[e];
#pragma unroll
    for (int d = 1; d < 64; d <<= 1) {
      int u = __shfl_up(v, d);
      if (lane >= d) v += u;
    }
    pre[e] = v - c[e];
    if (lane == 63) wbase[e][wv] = v;
  }
  __syncthreads();
  if (tid < NE) {
    int a = 0;
#pragma unroll
    for (int w = 0; w < 16; w++) { int v = wbase[tid][w]; wbase[tid][w] = a; a += v; }
    cnt[tid] = a;
    off[tid] = a;
  }
  __syncthreads();
  if (tid == 0) {
    int a = 0;
#pragma unroll
    for (int e = 0; e < NE; e++) { int v = off[e]; off[e] = a; a += v; }
  }
  __syncthreads();
  int t0 = tid * 8;
#pragma unroll
  for (int i = 0; i < 8; i++) {
    int e = sl[i];
    int r = 0;
#pragma unroll
    for (int q = 0; q < NE; q++)
      if (q == e) { r = off[q] + wbase[q][wv] + pre[q]; pre[q]++; }
    perm[r] = t0 + i;
  }
}

// ---- prep: gather + EXACT fp32 rw (dot + sigmoid) (blocks 0..8191) + cast ----
__global__ __launch_bounds__(256) void k_prep(const float* __restrict__ x,
                                              const float* __restrict__ gw,
                                              const int* __restrict__ sel,
                                              const int* __restrict__ perm,
                                              ushort* __restrict__ xs,
                                              const float4* __restrict__ wgate,
                                              const float4* __restrict__ wup,
                                              const float4* __restrict__ wdown,
                                              ushort4* __restrict__ wg_b,
                                              ushort4* __restrict__ wu_b,
                                              ushort4* __restrict__ wd_b) {
  __shared__ float psum[4];
  int b = blockIdx.x;
  int tid = threadIdx.x, wv = tid >> 6, lane = tid & 63;
  if (b < T_TOK) {
    int t = perm[b];
    int e = sel[t];
    float4 xv = ((const float4*)(x + (size_t)t * HD))[tid];
    float4 gv = ((const float4*)(gw + (size_t)e * HD))[tid];
    float p = xv.x * gv.x + xv.y * gv.y + xv.z * gv.z + xv.w * gv.w;
#pragma unroll
    for (int off = 32; off >= 1; off >>= 1) p += __shfl_xor(p, off);
    if (lane == 0) psum[wv] = p;
    __syncthreads();
    float logit = psum[0] + psum[1] + psum[2] + psum[3];
    float s = 1.0f / (1.0f + __expf(-logit));
    ushort4 o;
    o.x = f2bf(xv.x * s); o.y = f2bf(xv.y * s);
    o.z = f2bf(xv.z * s); o.w = f2bf(xv.w * s);
    ((ushort4*)(xs + (size_t)b * HD))[tid] = o;
  } else {
    int i = (b - T_TOK) * 256 + tid;
    float4 v; ushort4 r;
    v = wgate[i]; r.x = f2bf(v.x); r.y = f2bf(v.y); r.z = f2bf(v.z); r.w = f2bf(v.w); wg_b[i] = r;
    v = wup[i];   r.x = f2bf(v.x); r.y = f2bf(v.y); r.z = f2bf(v.z); r.w = f2bf(v.w); wu_b[i] = r;
    v = wdown[i]; r.x = f2bf(v.x); r.y = f2bf(v.y); r.z = f2bf(v.z); r.w = f2bf(v.w); wd_b[i] = r;
  }
}

// ---------------- fused gate+up GEMM -> h = u * silu(g) ----------
// BM=128 x BN=64, BK=64, expert pinned to XCD (e = blockIdx&7), 2 blocks/CU.
__global__ __launch_bounds__(256, 2) void k_gemm_gu(const ushort* __restrict__ xs,
                                                    const ushort* __restrict__ wg,
                                                    const ushort* __restrict__ wu,
                                                    const int* __restrict__ cnt,
                                                    ushort* __restrict__ h) {
  __shared__ __align__(16) ushort As[BM * BK];      // 16 KB
  __shared__ __align__(16) ushort Bg[GU_BN * BK];   // 8 KB
  __shared__ __align__(16) ushort Bu[GU_BN * BK];   // 8 KB

  int tid = threadIdx.x;
  int wv = tid >> 6, lane = tid & 63;
  int wm = wv >> 1, wn = wv & 1;
  int frow = lane & 15, khalf = lane >> 4;

  int e = blockIdx.x & 7;
  int cnte = cnt[e];
  int off = 0;
#pragma unroll
  for (int i = 0; i < NE; i++) off += (i < e) ? cnt[i] : 0;
  const ushort* wgE = wg + (size_t)e * ID * HD;
  const ushort* wuE = wu + (size_t)e * ID * HD;

  for (int idl = blockIdx.x >> 3; idl < GU_SPACE; idl += GU_BPE) {
    int mt = idl >> 3;
    int nt = idl & 7;
    if (mt * BM >= cnte) break;
    int m0 = off + mt * BM;
    int rv = cnte - mt * BM; if (rv > BM) rv = BM;
    int n0 = nt * GU_BN;

    const ushort* aBase = xs + (size_t)m0 * HD;
    const ushort* gBase = wgE + (size_t)n0 * HD;
    const ushort* uBase = wuE + (size_t)n0 * HD;

    f32x4 accg[4][2] = {};
    f32x4 accu[4][2] = {};

    for (int k0 = 0; k0 < HD; k0 += BK) {
      __syncthreads();
#pragma unroll
      for (int i = 0; i < 4; i++) {
        int ci = wv * 4 + i;
        stageChunk(aBase + (size_t)(ci * 8) * HD, HD, k0, &As[ci * 8 * BK], lane);
      }
#pragma unroll
      for (int i = 0; i < 2; i++) {
        int ci = wv * 2 + i;
        stageChunk(gBase + (size_t)(ci * 8) * HD, HD, k0, &Bg[ci * 8 * BK], lane);
        stageChunk(uBase + (size_t)(ci * 8) * HD, HD, k0, &Bu[ci * 8 * BK], lane);
      }
      __syncthreads();
      short8 af[2][4], bg[2][2], bu[2][2];
#pragma unroll
      for (int s = 0; s < 2; s++) {
        int g = s * 4 + khalf;
#pragma unroll
        for (int i = 0; i < 4; i++) af[s][i] = fragRd(As, wm * 64 + i * 16 + frow, g);
#pragma unroll
        for (int j = 0; j < 2; j++) {
          bg[s][j] = fragRd(Bg, wn * 32 + j * 16 + frow, g);
          bu[s][j] = fragRd(Bu, wn * 32 + j * 16 + frow, g);
        }
      }
#pragma unroll
      for (int s = 0; s < 2; s++)
#pragma unroll
        for (int i = 0; i < 4; i++)
#pragma unroll
          for (int j = 0; j < 2; j++) {
            accg[i][j] = __builtin_amdgcn_mfma_f32_16x16x32_bf16(af[s][i], bg[s][j], accg[i][j], 0, 0, 0);
            accu[i][j] = __builtin_amdgcn_mfma_f32_16x16x32_bf16(af[s][i], bu[s][j], accu[i][j], 0, 0, 0);
          }
    }

    int rb = wm * 64 + khalf * 4;
    int cb = n0 + wn * 32 + frow;
#pragma unroll
    for (int i = 0; i < 4; i++)
#pragma unroll
      for (int r = 0; r < 4; r++) {
        int m = rb + i * 16 + r;
        if (m < rv) {
          ushort* hrow = h + (size_t)(m0 + m) * ID + cb;
#pragma unroll
          for (int j = 0; j < 2; j++) {
            float g = accg[i][j][r], u = accu[i][j][r];
            float hv = u * g / (1.0f + __expf(-g));
            hrow[j * 16] = f2bf(hv);
          }
        }
      }
  }
}

// ---------------- down GEMM with row scatter ----------------
// BM=128 x BN=128, grid 512 (2 blocks/CU): stream = A x8 + B x8 = 128 MB.
__global__ __launch_bounds__(256, 2) void k_gemm_dn(const ushort* __restrict__ h,
                                                    const ushort* __restrict__ wd,
                                                    const int* __restrict__ cnt,
                                                    const int* __restrict__ perm,
                                                    float* __restrict__ out) {
  __shared__ __align__(16) ushort As[BM * BK];      // 16 KB
  __shared__ __align__(16) ushort Bs[DN_BN * BK];   // 16 KB

  int tid = threadIdx.x;
  int wv = tid >> 6, lane = tid & 63;
  int wm = wv >> 1, wn = wv & 1;
  int frow = lane & 15, khalf = lane >> 4;

  int e = blockIdx.x & 7;
  int cnte = cnt[e];
  int off = 0;
#pragma unroll
  for (int i = 0; i < NE; i++) off += (i < e) ? cnt[i] : 0;
  const ushort* wdE = wd + (size_t)e * HD * ID;

  for (int idl = blockIdx.x >> 3; idl < DN_SPACE; idl += DN_BPE) {
    int mt = idl >> 3;
    int nt = idl & 7;
    if (mt * BM >= cnte) break;
    int m0 = off + mt * BM;
    int rv = cnte - mt * BM; if (rv > BM) rv = BM;
    int n0 = nt * DN_BN;

    const ushort* aBase = h + (size_t)m0 * ID;
    const ushort* bBase = wdE + (size_t)n0 * ID;

    f32x4 acc[4][4] = {};

    for (int k0 = 0; k0 < ID; k0 += BK) {
      __syncthreads();
#pragma unroll
      for (int i = 0; i < 4; i++) {
        int ci = wv * 4 + i;
        stageChunk(aBase + (size_t)(ci * 8) * ID, ID, k0, &As[ci * 8 * BK], lane);
        stageChunk(bBase + (size_t)(ci * 8) * ID, ID, k0, &Bs[ci * 8 * BK], lane);
      }
      __syncthreads();
#pragma unroll
      for (int s = 0; s < 2; s++) {
        int g = s * 4 + khalf;
        short8 af[4], bf[4];
#pragma unroll
        for (int i = 0; i < 4; i++) af[i] = fragRd(As, wm * 64 + i * 16 + frow, g);
#pragma unroll
        for (int j = 0; j < 4; j++) bf[j] = fragRd(Bs, wn * 64 + j * 16 + frow, g);
#pragma unroll
        for (int i = 0; i < 4; i++)
#pragma unroll
          for (int j = 0; j < 4; j++)
            acc[i][j] = __builtin_amdgcn_mfma_f32_16x16x32_bf16(af[i], bf[j], acc[i][j], 0, 0, 0);
      }
    }

    int rb = wm * 64 + khalf * 4;
    int cb = n0 + wn * 64 + frow;
#pragma unroll
    for (int i = 0; i < 4; i++)
#pragma unroll
      for (int r = 0; r < 4; r++) {
        int m = rb + i * 16 + r;
        if (m < rv) {
          int t = perm[m0 + m];
          float* orow = out + (size_t)t * HD + cb;
#pragma unroll
          for (int j = 0; j < 4; j++) orow[j * 16] = acc[i][j][r];
        }
      }
  }
}

extern "C" void kernel_launch(void* const* d_in, const int* in_sizes, int n_in,
                              void* d_out, int out_size, void* d_ws, size_t ws_size,
                              hipStream_t stream) {
  const float* x     = (const float*)d_in[0];
  const float* gw    = (const float*)d_in[1];
  const float* wgate = (const float*)d_in[2];
  const float* wup   = (const float*)d_in[3];
  const float* wdown = (const float*)d_in[4];
  float* out = (float*)d_out;

  uint8_t* ws = (uint8_t*)d_ws;
  int*   cnt  = (int*)ws;                    // 8 ints
  int*   rcnt = (int*)(ws + 64);             // rescue counter
  int*   sel  = (int*)(ws + 256);
  int*   rlist = sel + T_TOK;                // reuse old rank slot (RESC_MAX ints)
  int*   perm = rlist + T_TOK;
  size_t o = 256 + (size_t)4 * 4 * T_TOK;
  ushort* wg_b = (ushort*)(ws + o); o += (size_t)NE * ID * HD * 2;
  ushort* wu_b = (ushort*)(ws + o); o += (size_t)NE * ID * HD * 2;
  ushort* wd_b = (ushort*)(ws + o); o += (size_t)NE * HD * ID * 2;
  ushort* xs   = (ushort*)(ws + o); o += (size_t)(T_TOK + BM) * HD * 2;
  ushort* hbuf = (ushort*)(ws + o); o += (size_t)(T_TOK + BM) * ID * 2;

  hipMemsetAsync(rcnt, 0, sizeof(int), stream);
  k_logits_sel<<<T_TOK / 16, 256, 0, stream>>>(x, gw, sel, rlist, rcnt);
  k_rescue<<<RESC_MAX / 4, 256, 0, stream>>>(x, gw, rlist, rcnt, sel);
  k_scan<<<1, 1024, 0, stream>>>(sel, cnt, perm);
  k_prep<<<T_TOK + CAST_BLOCKS, 256, 0, stream>>>(
      x, gw, sel, perm, xs,
      (const float4*)wgate, (const float4*)wup, (const float4*)wdown,
      (ushort4*)wg_b, (ushort4*)wu_b, (ushort4*)wd_b);
  k_gemm_gu<<<GU_GRID, 256, 0, stream>>>(xs, wg_b, wu_b, cnt, hbuf);
  k_gemm_dn<<<DN_GRID, 256, 0, stream>>>(hbuf, wd_b, cnt, perm, out);
}

// Round 10
// 204.304 us; speedup vs baseline: 1.0736x; 1.0736x over previous
//
#include <hip/hip_runtime.h>
#include <hip/hip_bf16.h>
#include <cstdint>
#include <cmath>

#define T_TOK 8192
#define HD 1024
#define ID 512
#define NE 8
#define BM 128
#define BK 64
#define MAXMT (T_TOK / BM)   // 64

#define GU_BN 64
#define GU_SPACE (MAXMT * (ID / GU_BN))   // 512; active ~64-72/expert
#define GU_BPE 64
#define GU_GRID (NE * GU_BPE)             // 512 -> 2 blocks/CU
#define DN_BN 128
#define DN_SPACE (MAXMT * (HD / DN_BN))   // 512; active ~64-72/expert
#define DN_BPE 64
#define DN_GRID (NE * DN_BPE)             // 512 -> 2 blocks/CU

#define FRONT_GRID 512
#define CAST_BLOCKS ((NE * ID * HD / 4) / 256)   // 4096
#define GAP_THR 0.06f

typedef __attribute__((ext_vector_type(8))) short short8;
typedef __attribute__((ext_vector_type(4))) float f32x4;

__device__ __forceinline__ unsigned short f2bf(float f) {
  union { float f; unsigned int u; } v; v.f = f;
  unsigned int u = v.u;
  u += 0x7fffu + ((u >> 16) & 1u);   // RNE
  return (unsigned short)(u >> 16);
}

#if __has_builtin(__builtin_amdgcn_global_load_lds)
#define HAVE_GLDS 1
#endif

// Global->LDS 16B/lane. LDS dest = wave-uniform base + lane*16.
__device__ __forceinline__ void stage16(const ushort* __restrict__ g,
                                        ushort* lds_wave_base, int lane) {
#ifdef HAVE_GLDS
  __builtin_amdgcn_global_load_lds((const __attribute__((address_space(1))) void*)g,
                                   (__attribute__((address_space(3))) void*)lds_wave_base,
                                   16, 0, 0);
#else
  *(uint4*)(lds_wave_base + (size_t)lane * 8) = *(const uint4*)g;
#endif
}

// BK=64: one glds instr stages 8 rows x 128B. Lane l -> row rl=l>>3, dest slot c=l&7.
// Slot c holds global colgroup c ^ (rl&7) (XOR swizzle; verified 0 bank conflicts).
__device__ __forceinline__ void stageChunk(const ushort* __restrict__ rowbase, size_t ld,
                                           int k0, ushort* ldsChunk, int lane) {
  int rl = lane >> 3;
  int gc = (lane & 7) ^ (rl & 7);
  stage16(rowbase + (size_t)rl * ld + k0 + gc * 8, ldsChunk, lane);
}

// Read 8-elem bf16 frag at (row r, global colgroup g), undoing swizzle.
__device__ __forceinline__ short8 fragRd(const ushort* buf, int r, int g) {
  int slot = g ^ (r & 7);
  return *(const short8*)&buf[r * BK + slot * 8];
}

__device__ __forceinline__ short8 cvt8(float4 a, float4 b) {
  short8 r;
  r[0] = (short)f2bf(a.x); r[1] = (short)f2bf(a.y);
  r[2] = (short)f2bf(a.z); r[3] = (short)f2bf(a.w);
  r[4] = (short)f2bf(b.x); r[5] = (short)f2bf(b.y);
  r[6] = (short)f2bf(b.z); r[7] = (short)f2bf(b.w);
  return r;
}

// ======= front: logits (MFMA) + argmax + inline fp64 rescue + exact rw +
//         gather (token-order xs, bf16) + weight-cast tail. ONE dispatch. =======
__global__ __launch_bounds__(256) void k_front(const float* __restrict__ x,
                                               const float* __restrict__ gw,
                                               int* __restrict__ sel,
                                               ushort* __restrict__ xs,
                                               const float4* __restrict__ wgate,
                                               const float4* __restrict__ wup,
                                               const float4* __restrict__ wdown,
                                               ushort4* __restrict__ wg_b,
                                               ushort4* __restrict__ wu_b,
                                               ushort4* __restrict__ wd_b) {
  __shared__ float red[4][16][16];
  __shared__ int selv[16];
  __shared__ int flist[16];
  __shared__ int fcnt;
  __shared__ double dred[4][NE];
  __shared__ float wvred[4][16];

  int tid = threadIdx.x, wv = tid >> 6, lane = tid & 63;
  int quad = lane >> 4, colv = lane & 15;
  int tb = blockIdx.x * 16;

  // ---- logits via bf16 MFMA; keep x chunks in registers ----
  const float* xrow = x + (size_t)(tb + colv) * HD + wv * 256 + quad * 8;
  const float* gwrow = gw + (size_t)(colv & 7) * HD + wv * 256 + quad * 8;
  float4 a[16];
  f32x4 acc = {};
  short8 bz = {};
  bool bvalid = colv < 8;
#pragma unroll
  for (int ks = 0; ks < 8; ks++) {
    a[2 * ks]     = *(const float4*)(xrow + ks * 32);
    a[2 * ks + 1] = *(const float4*)(xrow + ks * 32 + 4);
    short8 af = cvt8(a[2 * ks], a[2 * ks + 1]);
    short8 bf8 = bz;
    if (bvalid) {
      float4 b0 = *(const float4*)(gwrow + ks * 32);
      float4 b1 = *(const float4*)(gwrow + ks * 32 + 4);
      bf8 = cvt8(b0, b1);
    }
    acc = __builtin_amdgcn_mfma_f32_16x16x32_bf16(af, bf8, acc, 0, 0, 0);
  }
#pragma unroll
  for (int r = 0; r < 4; r++) red[wv][quad * 4 + r][colv] = acc[r];
  __syncthreads();
  int rr = tid >> 4, cc = tid & 15;
  float s4 = red[0][rr][cc] + red[1][rr][cc] + red[2][rr][cc] + red[3][rr][cc];
  __syncthreads();
  red[0][rr][cc] = s4;
  if (tid == 0) fcnt = 0;
  __syncthreads();
  if (tid < 16) {
    float best = -1e30f, sec = -1e30f; int bi = 0;
#pragma unroll
    for (int e = 0; e < NE; e++) {
      float v = red[0][tid][e];
      if (v > best) { sec = best; best = v; bi = e; }
      else if (v > sec) sec = v;
    }
    selv[tid] = bi;
    if (best - sec < GAP_THR) {
      int ix = atomicAdd(&fcnt, 1);
      flist[ix] = tid;   // local token index
    }
  }
  __syncthreads();

  // ---- inline fp64 rescue for narrow-gap tokens (rare) ----
  int nf = fcnt;
  for (int f = 0; f < nf; f++) {
    int tl = flist[f];
    int t = tb + tl;
    float4 xv = ((const float4*)(x + (size_t)t * HD))[tid];
    double p[NE];
#pragma unroll
    for (int e = 0; e < NE; e++) {
      float4 gv = ((const float4*)(gw + (size_t)e * HD))[tid];
      p[e] = (double)xv.x * gv.x + (double)xv.y * gv.y +
             (double)xv.z * gv.z + (double)xv.w * gv.w;
    }
#pragma unroll
    for (int e = 0; e < NE; e++)
      for (int off = 32; off >= 1; off >>= 1)
        p[e] += __shfl_xor(p[e], off);
    if (lane == 0)
#pragma unroll
      for (int e = 0; e < NE; e++) dred[wv][e] = p[e];
    __syncthreads();
    if (tid == 0) {
      double best = -1e300; int bi = 0;
#pragma unroll
      for (int e = 0; e < NE; e++) {
        double v = dred[0][e] + dred[1][e] + dred[2][e] + dred[3][e];
        if (v > best) { best = v; bi = e; }
      }
      selv[tl] = bi;
    }
    __syncthreads();
  }

  // ---- exact fp32 rw: dot(x[t], gw[sel[t]]) via 16-thread groups ----
  int se = selv[colv];
  const float* gsel = gw + (size_t)se * HD + wv * 256 + quad * 8;
  float p = 0.f;
#pragma unroll
  for (int ks = 0; ks < 8; ks++) {
    float4 g0 = *(const float4*)(gsel + ks * 32);
    float4 g1 = *(const float4*)(gsel + ks * 32 + 4);
    p += a[2 * ks].x * g0.x + a[2 * ks].y * g0.y + a[2 * ks].z * g0.z + a[2 * ks].w * g0.w;
    p += a[2 * ks + 1].x * g1.x + a[2 * ks + 1].y * g1.y + a[2 * ks + 1].z * g1.z + a[2 * ks + 1].w * g1.w;
  }
  p += __shfl_xor(p, 16);
  p += __shfl_xor(p, 32);
  if (quad == 0) wvred[wv][colv] = p;
  __syncthreads();
  float logit = wvred[0][colv] + wvred[1][colv] + wvred[2][colv] + wvred[3][colv];
  float sc = 1.0f / (1.0f + __expf(-logit));

  if (tid < 16) sel[tb + tid] = selv[tid];

  // ---- gather: xs[t] = bf16(x[t] * rw) in TOKEN order ----
  ushort* xd = xs + (size_t)(tb + colv) * HD + wv * 256 + quad * 8;
#pragma unroll
  for (int ks = 0; ks < 8; ks++) {
    float4 v0 = a[2 * ks], v1 = a[2 * ks + 1];
    short8 o;
    o[0] = (short)f2bf(v0.x * sc); o[1] = (short)f2bf(v0.y * sc);
    o[2] = (short)f2bf(v0.z * sc); o[3] = (short)f2bf(v0.w * sc);
    o[4] = (short)f2bf(v1.x * sc); o[5] = (short)f2bf(v1.y * sc);
    o[6] = (short)f2bf(v1.z * sc); o[7] = (short)f2bf(v1.w * sc);
    *(short8*)(xd + ks * 32) = o;
  }

  // ---- weight cast tail (grid-stride) ----
  for (int cb = blockIdx.x; cb < CAST_BLOCKS; cb += FRONT_GRID) {
    int i = cb * 256 + tid;
    float4 v; ushort4 r;
    v = wgate[i]; r.x = f2bf(v.x); r.y = f2bf(v.y); r.z = f2bf(v.z); r.w = f2bf(v.w); wg_b[i] = r;
    v = wup[i];   r.x = f2bf(v.x); r.y = f2bf(v.y); r.z = f2bf(v.z); r.w = f2bf(v.w); wu_b[i] = r;
    v = wdown[i]; r.x = f2bf(v.x); r.y = f2bf(v.y); r.z = f2bf(v.z); r.w = f2bf(v.w); wd_b[i] = r;
  }
}

// ---------------- single-block count + scan + permutation (no atomics) ----------
__global__ __launch_bounds__(1024) void k_scan(const int* __restrict__ sel,
                                               int* __restrict__ cnt,
                                               int* __restrict__ perm) {
  __shared__ int wbase[NE][16];
  __shared__ int off[NE];
  int tid = threadIdx.x;
  int wv = tid >> 6, lane = tid & 63;

  int4 s0 = ((const int4*)sel)[tid * 2];
  int4 s1 = ((const int4*)sel)[tid * 2 + 1];
  int sl[8] = {s0.x, s0.y, s0.z, s0.w, s1.x, s1.y, s1.z, s1.w};

  int c[NE];
#pragma unroll
  for (int e = 0; e < NE; e++) c[e] = 0;
#pragma unroll
  for (int i = 0; i < 8; i++)
#pragma unroll
    for (int e = 0; e < NE; e++) c[e] += (sl[i] == e) ? 1 : 0;

  int pre[NE];
#pragma unroll
  for (int e = 0; e < NE; e++) {
    int v = c[e];
#pragma unroll
    for (int d = 1; d < 64; d <<= 1) {
      int u = __shfl_up(v, d);
      if (lane >= d) v += u;
    }
    pre[e] = v - c[e];
    if (lane == 63) wbase[e][wv] = v;
  }
  __syncthreads();
  if (tid < NE) {
    int a = 0;
#pragma unroll
    for (int w = 0; w < 16; w++) { int v = wbase[tid][w]; wbase[tid][w] = a; a += v; }
    cnt[tid] = a;
    off[tid] = a;
  }
  __syncthreads();
  if (tid == 0) {
    int a = 0;
#pragma unroll
    for (int e = 0; e < NE; e++) { int v = off[e]; off[e] = a; a += v; }
  }
  __syncthreads();
  int t0 = tid * 8;
#pragma unroll
  for (int i = 0; i < 8; i++) {
    int e = sl[i];
    int r = 0;
#pragma unroll
    for (int q = 0; q < NE; q++)
      if (q == e) { r = off[q] + wbase[q][wv] + pre[q]; pre[q]++; }
    perm[r] = t0 + i;
  }
}

// ---------------- fused gate+up GEMM -> h = u * silu(g) ----------
// A rows gathered via perm indirection (xs is token-ordered). h stays in
// permuted row space. BM=128 x BN=64, BK=64, expert->XCD, 2 blocks/CU.
__global__ __launch_bounds__(256, 2) void k_gemm_gu(const ushort* __restrict__ xs,
                                                    const ushort* __restrict__ wg,
                                                    const ushort* __restrict__ wu,
                                                    const int* __restrict__ cnt,
                                                    const int* __restrict__ perm,
                                                    ushort* __restrict__ h) {
  __shared__ __align__(16) ushort As[BM * BK];      // 16 KB
  __shared__ __align__(16) ushort Bg[GU_BN * BK];   // 8 KB
  __shared__ __align__(16) ushort Bu[GU_BN * BK];   // 8 KB

  int tid = threadIdx.x;
  int wv = tid >> 6, lane = tid & 63;
  int wm = wv >> 1, wn = wv & 1;
  int frow = lane & 15, khalf = lane >> 4;
  int rl = lane >> 3;
  int gc = (lane & 7) ^ (rl & 7);

  int e = blockIdx.x & 7;
  int cnte = cnt[e];
  int off = 0;
#pragma unroll
  for (int i = 0; i < NE; i++) off += (i < e) ? cnt[i] : 0;
  const ushort* wgE = wg + (size_t)e * ID * HD;
  const ushort* wuE = wu + (size_t)e * ID * HD;

  for (int idl = blockIdx.x >> 3; idl < GU_SPACE; idl += GU_BPE) {
    int mt = idl >> 3;
    int nt = idl & 7;
    if (mt * BM >= cnte) break;
    int m0 = off + mt * BM;
    int rv = cnte - mt * BM; if (rv > BM) rv = BM;
    int n0 = nt * GU_BN;

    // per-lane A row indices for this tile (clamped; rows>=rv compute garbage, masked at store)
    int ar[4];
#pragma unroll
    for (int i = 0; i < 4; i++) {
      int pr = m0 + (wv * 4 + i) * 8 + rl;
      if (pr > T_TOK - 1) pr = T_TOK - 1;
      ar[i] = perm[pr];
    }

    const ushort* gBase = wgE + (size_t)n0 * HD;
    const ushort* uBase = wuE + (size_t)n0 * HD;

    f32x4 accg[4][2] = {};
    f32x4 accu[4][2] = {};

    for (int k0 = 0; k0 < HD; k0 += BK) {
      __syncthreads();
#pragma unroll
      for (int i = 0; i < 4; i++) {
        int ci = wv * 4 + i;
        stage16(xs + (size_t)ar[i] * HD + k0 + gc * 8, &As[ci * 8 * BK], lane);
      }
#pragma unroll
      for (int i = 0; i < 2; i++) {
        int ci = wv * 2 + i;
        stageChunk(gBase + (size_t)(ci * 8) * HD, HD, k0, &Bg[ci * 8 * BK], lane);
        stageChunk(uBase + (size_t)(ci * 8) * HD, HD, k0, &Bu[ci * 8 * BK], lane);
      }
      __syncthreads();
      short8 af[2][4], bg[2][2], bu[2][2];
#pragma unroll
      for (int s = 0; s < 2; s++) {
        int g = s * 4 + khalf;
#pragma unroll
        for (int i = 0; i < 4; i++) af[s][i] = fragRd(As, wm * 64 + i * 16 + frow, g);
#pragma unroll
        for (int j = 0; j < 2; j++) {
          bg[s][j] = fragRd(Bg, wn * 32 + j * 16 + frow, g);
          bu[s][j] = fragRd(Bu, wn * 32 + j * 16 + frow, g);
        }
      }
#pragma unroll
      for (int s = 0; s < 2; s++)
#pragma unroll
        for (int i = 0; i < 4; i++)
#pragma unroll
          for (int j = 0; j < 2; j++) {
            accg[i][j] = __builtin_amdgcn_mfma_f32_16x16x32_bf16(af[s][i], bg[s][j], accg[i][j], 0, 0, 0);
            accu[i][j] = __builtin_amdgcn_mfma_f32_16x16x32_bf16(af[s][i], bu[s][j], accu[i][j], 0, 0, 0);
          }
    }

    int rb = wm * 64 + khalf * 4;
    int cb = n0 + wn * 32 + frow;
#pragma unroll
    for (int i = 0; i < 4; i++)
#pragma unroll
      for (int r = 0; r < 4; r++) {
        int m = rb + i * 16 + r;
        if (m < rv) {
          ushort* hrow = h + (size_t)(m0 + m) * ID + cb;
#pragma unroll
          for (int j = 0; j < 2; j++) {
            float g = accg[i][j][r], u = accu[i][j][r];
            float hv = u * g / (1.0f + __expf(-g));
            hrow[j * 16] = f2bf(hv);
          }
        }
      }
  }
}

// ---------------- down GEMM with row scatter ----------------
// BM=128 x BN=128, grid 512 (2 blocks/CU): stream = A x8 + B x8 = 128 MB.
__global__ __launch_bounds__(256, 2) void k_gemm_dn(const ushort* __restrict__ h,
                                                    const ushort* __restrict__ wd,
                                                    const int* __restrict__ cnt,
                                                    const int* __restrict__ perm,
                                                    float* __restrict__ out) {
  __shared__ __align__(16) ushort As[BM * BK];      // 16 KB
  __shared__ __align__(16) ushort Bs[DN_BN * BK];   // 16 KB

  int tid = threadIdx.x;
  int wv = tid >> 6, lane = tid & 63;
  int wm = wv >> 1, wn = wv & 1;
  int frow = lane & 15, khalf = lane >> 4;

  int e = blockIdx.x & 7;
  int cnte = cnt[e];
  int off = 0;
#pragma unroll
  for (int i = 0; i < NE; i++) off += (i < e) ? cnt[i] : 0;
  const ushort* wdE = wd + (size_t)e * HD * ID;

  for (int idl = blockIdx.x >> 3; idl < DN_SPACE; idl += DN_BPE) {
    int mt = idl >> 3;
    int nt = idl & 7;
    if (mt * BM >= cnte) break;
    int m0 = off + mt * BM;
    int rv = cnte - mt * BM; if (rv > BM) rv = BM;
    int n0 = nt * DN_BN;

    const ushort* aBase = h + (size_t)m0 * ID;
    const ushort* bBase = wdE + (size_t)n0 * ID;

    f32x4 acc[4][4] = {};

    for (int k0 = 0; k0 < ID; k0 += BK) {
      __syncthreads();
#pragma unroll
      for (int i = 0; i < 4; i++) {
        int ci = wv * 4 + i;
        stageChunk(aBase + (size_t)(ci * 8) * ID, ID, k0, &As[ci * 8 * BK], lane);
        stageChunk(bBase + (size_t)(ci * 8) * ID, ID, k0, &Bs[ci * 8 * BK], lane);
      }
      __syncthreads();
#pragma unroll
      for (int s = 0; s < 2; s++) {
        int g = s * 4 + khalf;
        short8 af[4], bf[4];
#pragma unroll
        for (int i = 0; i < 4; i++) af[i] = fragRd(As, wm * 64 + i * 16 + frow, g);
#pragma unroll
        for (int j = 0; j < 4; j++) bf[j] = fragRd(Bs, wn * 64 + j * 16 + frow, g);
#pragma unroll
        for (int i = 0; i < 4; i++)
#pragma unroll
          for (int j = 0; j < 4; j++)
            acc[i][j] = __builtin_amdgcn_mfma_f32_16x16x32_bf16(af[i], bf[j], acc[i][j], 0, 0, 0);
      }
    }

    int rb = wm * 64 + khalf * 4;
    int cb = n0 + wn * 64 + frow;
#pragma unroll
    for (int i = 0; i < 4; i++)
#pragma unroll
      for (int r = 0; r < 4; r++) {
        int m = rb + i * 16 + r;
        if (m < rv) {
          int t = perm[m0 + m];
          float* orow = out + (size_t)t * HD + cb;
#pragma unroll
          for (int j = 0; j < 4; j++) orow[j * 16] = acc[i][j][r];
        }
      }
  }
}

extern "C" void kernel_launch(void* const* d_in, const int* in_sizes, int n_in,
                              void* d_out, int out_size, void* d_ws, size_t ws_size,
                              hipStream_t stream) {
  const float* x     = (const float*)d_in[0];
  const float* gw    = (const float*)d_in[1];
  const float4* wgate = (const float4*)d_in[2];
  const float4* wup   = (const float4*)d_in[3];
  const float4* wdown = (const float4*)d_in[4];
  float* out = (float*)d_out;

  uint8_t* ws = (uint8_t*)d_ws;
  int*   cnt  = (int*)ws;                    // 8 ints
  int*   sel  = (int*)(ws + 256);
  int*   perm = sel + 2 * T_TOK;
  size_t o = 256 + (size_t)4 * 4 * T_TOK;
  ushort4* wg_b = (ushort4*)(ws + o); o += (size_t)NE * ID * HD * 2;
  ushort4* wu_b = (ushort4*)(ws + o); o += (size_t)NE * ID * HD * 2;
  ushort4* wd_b = (ushort4*)(ws + o); o += (size_t)NE * HD * ID * 2;
  ushort* xs   = (ushort*)(ws + o); o += (size_t)(T_TOK + BM) * HD * 2;
  ushort* hbuf = (ushort*)(ws + o); o += (size_t)(T_TOK + BM) * ID * 2;

  k_front<<<FRONT_GRID, 256, 0, stream>>>(x, gw, sel, xs, wgate, wup, wdown,
                                          (ushort4*)wg_b, (ushort4*)wu_b, (ushort4*)wd_b);
  k_scan<<<1, 1024, 0, stream>>>(sel, cnt, perm);
  k_gemm_gu<<<GU_GRID, 256, 0, stream>>>(xs, (const ushort*)wg_b, (const ushort*)wu_b,
                                         cnt, perm, hbuf);
  k_gemm_dn<<<DN_GRID, 256, 0, stream>>>(hbuf, (const ushort*)wd_b, cnt, perm, out);
}